// Round 13
// baseline (675.499 us; speedup 1.0000x reference)
//
#include <hip/hip_runtime.h>
#include <stdint.h>

using bf16x8 = __attribute__((ext_vector_type(8))) __bf16;
using f32x4  = __attribute__((ext_vector_type(4))) float;

#define DEVI __device__ __forceinline__

DEVI unsigned short f2b(float f) {
  unsigned int u = __builtin_bit_cast(unsigned int, f);
  u = (u + 0x7FFFu + ((u >> 16) & 1u)) >> 16;
  return (unsigned short)u;
}
DEVI float b2f(unsigned short h) {
  unsigned int u = ((unsigned int)h) << 16;
  return __builtin_bit_cast(float, u);
}
DEVI f32x4 mfma16(bf16x8 a, bf16x8 b, f32x4 c) {
  return __builtin_amdgcn_mfma_f32_16x16x32_bf16(a, b, c, 0, 0, 0);
}
#define GLD(gp, lp) __builtin_amdgcn_global_load_lds( \
    (__attribute__((address_space(1))) void*)(uintptr_t)(gp), \
    (__attribute__((address_space(3))) void*)(uintptr_t)(lp), 16, 0, 0)

static constexpr int S_LEN = 2048;
static constexpr int HDIM  = 2048;
static constexpr int NH    = 16;
static constexpr int NKV   = 8;
static constexpr int HD    = 128;
static constexpr int IFF   = 5632;
static constexpr int WIN   = 1024;

// ---------------------------------------------------------------- RMSNorm core
DEVI void rms_finish(float4 v0, float4 v1, const float* __restrict__ w,
                     void* __restrict__ outp, int s, int t, int outf32) {
  float ss = v0.x*v0.x + v0.y*v0.y + v0.z*v0.z + v0.w*v0.w +
             v1.x*v1.x + v1.y*v1.y + v1.z*v1.z + v1.w*v1.w;
  #pragma unroll
  for (int off = 32; off >= 1; off >>= 1) ss += __shfl_xor(ss, off, 64);
  __shared__ float red[4];
  if ((t & 63) == 0) red[t >> 6] = ss;
  __syncthreads();
  ss = red[0] + red[1] + red[2] + red[3];
  float rr = rsqrtf(ss * (1.0f / 2048.0f) + 1e-6f);
  const float4* w4 = (const float4*)w;
  float4 w0 = w4[t], w1 = w4[t + 256];
  float o0x = v0.x*rr*w0.x, o0y = v0.y*rr*w0.y, o0z = v0.z*rr*w0.z, o0w = v0.w*rr*w0.w;
  float o1x = v1.x*rr*w1.x, o1y = v1.y*rr*w1.y, o1z = v1.z*rr*w1.z, o1w = v1.w*rr*w1.w;
  if (outf32) {
    float4* o4 = (float4*)outp + (size_t)s * 512;
    o4[t]       = make_float4(o0x, o0y, o0z, o0w);
    o4[t + 256] = make_float4(o1x, o1y, o1z, o1w);
  } else {
    uint2* ob = (uint2*)((unsigned short*)outp + (size_t)s * HDIM);
    ob[t]       = make_uint2((unsigned)f2b(o0x) | ((unsigned)f2b(o0y) << 16),
                             (unsigned)f2b(o0z) | ((unsigned)f2b(o0w) << 16));
    ob[t + 256] = make_uint2((unsigned)f2b(o1x) | ((unsigned)f2b(o1y) << 16),
                             (unsigned)f2b(o1z) | ((unsigned)f2b(o1w) << 16));
  }
}

// ---------------------------------------------------------------- gather + rope tables + layer0 ln1
__global__ __launch_bounds__(256) void gather_kernel(const int* __restrict__ ids,
    const float* __restrict__ embed, float* __restrict__ x,
    float* __restrict__ ct, float* __restrict__ st,
    const float* __restrict__ ln1w, unsigned short* __restrict__ h) {
  int s = blockIdx.x, t = threadIdx.x;
  const float4* src = (const float4*)(embed + (size_t)ids[s] * HDIM);
  float4* dst = (float4*)(x + (size_t)s * HDIM);
  float4 v0 = src[t], v1 = src[t + 256];
  dst[t]       = v0;
  dst[t + 256] = v1;
  if (t < 64) {
    float inv = expf(-(float)t * (9.210340371976184f / 64.0f));  // theta^(-t/64)
    float f = (float)s * inv;
    ct[s * 64 + t] = cosf(f);
    st[s * 64 + t] = sinf(f);
  }
  rms_finish(v0, v1, ln1w, h, s, t, 0);   // layer-0 ln1 output (bf16)
}

// x += sum of NPARTS K-split partials (bf16, fixed order), then norm.
template<int OUTF32, int NPARTS>
__global__ __launch_bounds__(256) void rmsnorm_combine_kernel(
    float* __restrict__ x, const unsigned short* __restrict__ parts,
    const float* __restrict__ w, void* __restrict__ outp) {
  int s = blockIdx.x, t = threadIdx.x;
  const size_t PS = (size_t)2048 * 2048;
  float4* row = (float4*)(x + (size_t)s * HDIM);
  float4 v0 = row[t], v1 = row[t + 256];
  #pragma unroll
  for (int p = 0; p < NPARTS; ++p) {
    const unsigned short* pr = parts + p * PS + (size_t)s * HDIM;
    uint2 a = *(const uint2*)(pr + t * 4);
    uint2 b = *(const uint2*)(pr + (t + 256) * 4);
    v0.x += b2f((unsigned short)a.x); v0.y += b2f((unsigned short)(a.x >> 16));
    v0.z += b2f((unsigned short)a.y); v0.w += b2f((unsigned short)(a.y >> 16));
    v1.x += b2f((unsigned short)b.x); v1.y += b2f((unsigned short)(b.x >> 16));
    v1.z += b2f((unsigned short)b.y); v1.w += b2f((unsigned short)(b.y >> 16));
  }
  row[t] = v0; row[t + 256] = v1;
  rms_finish(v0, v1, w, outp, s, t, OUTF32);
}

// ---------------------------------------------------------------- weight transpose+cvt
// [128 k][64 n] input tiles -> out[n][k] bf16, packed u32 stores.
// Wg/Wu packed interleaved by 128-feature blocks (for fused silu epilogue).
__global__ __launch_bounds__(256) void convert_weights_kernel(
    const float* __restrict__ Wq, const float* __restrict__ Wk,
    const float* __restrict__ Wv, const float* __restrict__ Wo,
    const float* __restrict__ Wg, const float* __restrict__ Wu,
    const float* __restrict__ Wd,
    unsigned short* wqkvT, unsigned short* woT,
    unsigned short* wguT, unsigned short* wdT) {
  __shared__ float tl[128 * 65];
  int b = blockIdx.x;
  const float* in; unsigned short* out; int istr, ostr, tilesN, t; int guAdd = -1;
  if (b < 512)       { in = Wq; out = wqkvT;                       istr = 2048; ostr = 2048; tilesN = 32; t = b; }
  else if (b < 768)  { in = Wk; out = wqkvT + (size_t)2048 * 2048; istr = 1024; ostr = 2048; tilesN = 16; t = b - 512; }
  else if (b < 1024) { in = Wv; out = wqkvT + (size_t)3072 * 2048; istr = 1024; ostr = 2048; tilesN = 16; t = b - 768; }
  else if (b < 1536) { in = Wo; out = woT;                         istr = 2048; ostr = 2048; tilesN = 32; t = b - 1024; }
  else if (b < 2944) { in = Wg; out = wguT;                        istr = 5632; ostr = 2048; tilesN = 88; t = b - 1536; guAdd = 0; }
  else if (b < 4352) { in = Wu; out = wguT;                        istr = 5632; ostr = 2048; tilesN = 88; t = b - 2944; guAdd = 128; }
  else               { in = Wd; out = wdT;                         istr = 2048; ostr = 5632; tilesN = 32; t = b - 4352; }
  int k0 = (t / tilesN) * 128, n0 = (t % tilesN) * 64;
  int tx = threadIdx.x & 63, ty = threadIdx.x >> 6;
  #pragma unroll
  for (int i = 0; i < 32; ++i)
    tl[(ty + 4 * i) * 65 + tx] = in[(size_t)(k0 + ty + 4 * i) * istr + (n0 + tx)];
  __syncthreads();
  int ob = (guAdd >= 0) ? (((n0 >> 7) << 8) + (n0 & 64) + guAdd) : n0;
  unsigned int* ou = (unsigned int*)out;
  const int kstr2 = ostr >> 1;
  #pragma unroll
  for (int i = 0; i < 16; ++i) {
    int nrow = ty + 4 * i;
    float lo = tl[(2 * tx) * 65 + nrow], hi = tl[(2 * tx + 1) * 65 + nrow];
    ou[(size_t)(ob + nrow) * kstr2 + (k0 >> 1) + tx] =
        (unsigned int)f2b(lo) | ((unsigned int)f2b(hi) << 16);
  }
}

// ---------------------------------------------------------------- shared GEMM helpers
DEVI bf16x8 ldsAB(const unsigned short* buf, int r, int cbyte) {
  return *(const bf16x8*)((const unsigned char*)buf + r * 128 + (cbyte ^ ((r & 7) << 4)));
}
DEVI void stage_unit(const unsigned short* __restrict__ G, int Kstr,
                     unsigned short* lbuf, int loff0, int grow0,
                     int loff1, int grow1, int w, int l) {
  const int rsub = l >> 3;
  const int ce = ((l & 7) ^ rsub) << 3;           // pre-swizzled source col
  const unsigned short* s0 = G + (size_t)(grow0 + w * 8 + rsub) * Kstr + ce;
  GLD(s0, (unsigned char*)lbuf + loff0 + w * 1024 + l * 16);
  const unsigned short* s1 = G + (size_t)(grow1 + w * 8 + rsub) * Kstr + ce;
  GLD(s1, (unsigned char*)lbuf + loff1 + w * 1024 + l * 16);
}

// ---------------------------------------------------------------- 128x256 deep-pipelined GEMM (R10-proven)
// 8 waves (2Mx4N), BK=64. ONE barrier per K-tile, race-free by construction:
// B is TRIPLE-buffered (slot = k mod 3, rotating pointers), A double (parity).
template<int Q>
DEVI void phase128(const unsigned short* Ab, f32x4 (&acc)[4][4],
                   bf16x8 (&breg)[2][4], int wr, int lg, int li) {
  const int r0 = wr * 64 + Q * 16 + li;
  bf16x8 a0 = ldsAB(Ab, r0, lg * 16);
  bf16x8 a1 = ldsAB(Ab, r0, 64 + lg * 16);
  __builtin_amdgcn_s_setprio(1);
  #pragma unroll
  for (int n = 0; n < 4; ++n) acc[Q][n] = mfma16(a0, breg[0][n], acc[Q][n]);
  #pragma unroll
  for (int n = 0; n < 4; ++n) acc[Q][n] = mfma16(a1, breg[1][n], acc[Q][n]);
  __builtin_amdgcn_s_setprio(0);
}

// EPI: 0 = bf16 partial store; 3 = fused silu(g)*u; 4 = qkv epilogue
template<int EPI>
__global__ __launch_bounds__(512, 1) void gemm128_kernel(
    const unsigned short* __restrict__ A, const unsigned short* __restrict__ Bt,
    void* __restrict__ Cout, int Kstr, int nt, int parts, int nbm, int ldc,
    long long partStride,
    const float* __restrict__ ct, const float* __restrict__ st,
    unsigned short* __restrict__ ko, unsigned short* __restrict__ vt) {
  __shared__ __align__(16) unsigned char smem[131072];
  unsigned short* As0 = (unsigned short*)smem;             // [2][128*64] elems (16KB each)
  unsigned short* Bs0 = (unsigned short*)(smem + 32768);   // [3][256*64] elems (32KB each)
  const int tid = threadIdx.x, l = tid & 63, w = tid >> 6;
  const int lg = l >> 4, li = l & 15;
  const int wr = w >> 2, wc = w & 3;
  const int nb = gridDim.x, qx = nb >> 3;
  const int wg = ((int)blockIdx.x & 7) * qx + ((int)blockIdx.x >> 3);  // XCD swizzle (nb%8==0)
  const int nbT = nb / parts;
  const int tile = wg % nbT, part = wg / nbT;
  const int m0 = (tile % nbm) * 128, n0 = (tile / nbm) * 256;  // column-major: B-panel L2 reuse
  const int kOff = part * (nt << 6);
  const unsigned short* At  = A  + (size_t)m0 * Kstr + kOff;
  const unsigned short* Bto = Bt + (size_t)n0 * Kstr + kOff;
  f32x4 acc[4][4] = {};
  bf16x8 breg[2][4];
  unsigned short* B0p = Bs0;                // holds B(t)   (read slot)
  unsigned short* B1p = Bs0 + 16384;        // holds B(t+1)
  unsigned short* B2p = Bs0 + 32768;        // stage target B(t+2)

  // prologue: B(0)x4, A(0)x2, B(1)x4 -> vmcnt(4) retires B(0)+A(0); barrier publishes
  stage_unit(Bto, Kstr, B0p, 0, 0, 8192, 64, w, l);
  stage_unit(Bto, Kstr, B0p, 16384, 128, 24576, 192, w, l);
  stage_unit(At,  Kstr, As0, 0, 0, 8192, 64, w, l);
  { int k1 = (nt > 1) ? 64 : 0;
    stage_unit(Bto + k1, Kstr, B1p, 0, 0, 8192, 64, w, l);
    stage_unit(Bto + k1, Kstr, B1p, 16384, 128, 24576, 192, w, l); }
  asm volatile("s_waitcnt vmcnt(4)\n\ts_barrier" ::: "memory");

  for (int t = 0; t < nt; ++t) {
    unsigned short* Ab  = As0 + (t & 1) * 8192;
    unsigned short* Abn = As0 + ((t & 1) ^ 1) * 8192;
    const int kt1 = ((t + 1 < nt) ? t + 1 : nt - 1) << 6;   // clamped tail keeps queue uniform
    const int kt2 = ((t + 2 < nt) ? t + 2 : nt - 1) << 6;
    // ph0: stage A(t+1) -> other A slot; breg(t) from B0p (published last barrier)
    stage_unit(At + kt1, Kstr, Abn, 0, 0, 8192, 64, w, l);
    #pragma unroll
    for (int ks = 0; ks < 2; ++ks)
      #pragma unroll
      for (int n = 0; n < 4; ++n)
        breg[ks][n] = ldsAB(B0p, wc * 64 + n * 16 + li, ks * 64 + lg * 16);
    phase128<0>(Ab, acc, breg, wr, lg, li);
    // ph1: stage B0(t+2) -> B2p (dead slot; no read conflict this tile)
    stage_unit(Bto + kt2, Kstr, B2p, 0, 0, 8192, 64, w, l);
    phase128<1>(Ab, acc, breg, wr, lg, li);
    // ph2: stage B1(t+2) -> B2p
    stage_unit(Bto + kt2, Kstr, B2p, 16384, 128, 24576, 192, w, l);
    phase128<2>(Ab, acc, breg, wr, lg, li);
    // ph3
    phase128<3>(Ab, acc, breg, wr, lg, li);
    // single per-tile sync: retires B(t+1)+A(t+1) in every wave, then publishes
    asm volatile("s_waitcnt vmcnt(4) lgkmcnt(0)\n\ts_barrier" ::: "memory");
    unsigned short* tmp = B0p; B0p = B1p; B1p = B2p; B2p = tmp;
  }
  asm volatile("s_waitcnt vmcnt(0)" ::: "memory");

  if (EPI == 0) {
    unsigned short* C = (unsigned short*)Cout + (size_t)part * (size_t)partStride;
    #pragma unroll
    for (int m = 0; m < 4; ++m)
      #pragma unroll
      for (int n = 0; n < 4; ++n) {
        int col = n0 + wc * 64 + n * 16 + li;
        #pragma unroll
        for (int r = 0; r < 4; ++r) {
          int row = m0 + wr * 64 + m * 16 + lg * 4 + r;
          C[(size_t)row * ldc + col] = f2b(acc[m][n][r]);
        }
      }
  } else if (EPI == 3) {
    // fused silu: tile cols [0,128) = G features, [128,256) = matching U.
    float* ub = (float*)smem;   // [128][128] f32 = 64KB (LDS reuse after drain)
    asm volatile("s_barrier" ::: "memory");
    if (wc >= 2) {
      #pragma unroll
      for (int m = 0; m < 4; ++m)
        #pragma unroll
        for (int n = 0; n < 4; ++n) {
          int colL = (wc - 2) * 64 + n * 16 + li;
          #pragma unroll
          for (int r = 0; r < 4; ++r) {
            int rowl = wr * 64 + m * 16 + lg * 4 + r;
            ub[rowl * 128 + colL] = acc[m][n][r];
          }
        }
    }
    asm volatile("s_waitcnt lgkmcnt(0)\n\ts_barrier" ::: "memory");
    if (wc < 2) {
      unsigned short* act = (unsigned short*)Cout;
      const int col0 = n0 >> 1;
      #pragma unroll
      for (int m = 0; m < 4; ++m)
        #pragma unroll
        for (int n = 0; n < 4; ++n) {
          int colL = wc * 64 + n * 16 + li;
          #pragma unroll
          for (int r = 0; r < 4; ++r) {
            int rowl = wr * 64 + m * 16 + lg * 4 + r;
            float g = acc[m][n][r];
            float u = ub[rowl * 128 + colL];
            act[(size_t)(m0 + rowl) * ldc + col0 + colL] =
                f2b(g / (1.0f + __expf(-g)) * u);
          }
        }
    }
  } else {
    // EPI == 4: qkv epilogue. Dump acc to LDS f32 [128][256], then per region:
    // Q/K: RoPE with partner at colL^64 -> bf16. V: transposed write to vt[d][s].
    float* dump = (float*)smem;
    asm volatile("s_barrier" ::: "memory");       // all waves drained vmcnt(0)
    #pragma unroll
    for (int m = 0; m < 4; ++m)
      #pragma unroll
      for (int n = 0; n < 4; ++n) {
        int colL = wc * 64 + n * 16 + li;
        #pragma unroll
        for (int r = 0; r < 4; ++r) {
          int rowl = wr * 64 + m * 16 + lg * 4 + r;
          dump[rowl * 256 + colL] = acc[m][n][r];
        }
      }
    asm volatile("s_waitcnt lgkmcnt(0)\n\ts_barrier" ::: "memory");
    if (n0 < 3072) {
      unsigned short* qk = (n0 < 2048) ? (unsigned short*)Cout : ko;
      const int cbase = (n0 < 2048) ? n0 : (n0 - 2048);
      const int ostr  = (n0 < 2048) ? 2048 : 1024;
      #pragma unroll
      for (int m = 0; m < 4; ++m)
        #pragma unroll
        for (int n = 0; n < 4; ++n) {
          int colL = wc * 64 + n * 16 + li;
          int hi = colL & 64;
          #pragma unroll
          for (int r = 0; r < 4; ++r) {
            int rowl = wr * 64 + m * 16 + lg * 4 + r;
            int s = m0 + rowl;
            float own = dump[rowl * 256 + colL];
            float par = dump[rowl * 256 + (colL ^ 64)];
            float c  = ct[s * 64 + (colL & 63)];
            float sn = st[s * 64 + (colL & 63)];
            float v = hi ? (own * c + par * sn) : (own * c - par * sn);
            qk[(size_t)s * ostr + cbase + colL] = f2b(v);
          }
        }
    } else {
      // 512 threads -> 256 vcols x 2 s-halves; 64 bf16 (128B) contiguous per thread
      int vcol = tid >> 1, sh = (tid & 1) * 64;
      unsigned short* dstp = vt + (size_t)(n0 - 3072 + vcol) * 2048 + m0 + sh;
      #pragma unroll
      for (int c8 = 0; c8 < 8; ++c8) {
        unsigned short pk[8];
        #pragma unroll
        for (int i = 0; i < 8; ++i)
          pk[i] = f2b(dump[(sh + c8 * 8 + i) * 256 + vcol]);
        *(uint4*)(dstp + c8 * 8) = *(const uint4*)pk;
      }
    }
  }
}

// ---------------------------------------------------------------- sliding-window flash attention v3
// 256 threads, 4 waves, ONE q-head per block; grid (32 q-tiles, 16 heads) =
// 512 blocks -> 2 blocks/CU: scheduler balances the 1..17-tile window spread
// and cross-block overlap hides staging drains. Double-buffered K/V + T13.
DEVI void stageKV(const unsigned short* __restrict__ kg,
                  const unsigned short* __restrict__ vtg, int kv, int j0,
                  unsigned short* Kbuf, unsigned short* Vbuf, int w, int l) {
  #pragma unroll
  for (int p = 0; p < 4; ++p) {
    int off = p * 4096 + w * 1024 + l * 16;
    int row = off >> 8;
    int colb = (off & 255) ^ ((row & 7) << 4);
    GLD(kg + (size_t)(j0 + row) * (NKV * HD) + kv * HD + (colb >> 1),
        (unsigned char*)Kbuf + off);
  }
  #pragma unroll
  for (int p = 0; p < 4; ++p) {
    int off = p * 4096 + w * 1024 + l * 16;
    int d = off >> 7;
    int colb = (off & 127) ^ ((d & 7) << 4);
    GLD(vtg + (size_t)(kv * HD + d) * S_LEN + j0 + (colb >> 1),
        (unsigned char*)Vbuf + off);
  }
}

__global__ __launch_bounds__(256) void attn_kernel(
    const unsigned short* __restrict__ qg, const unsigned short* __restrict__ kg,
    const unsigned short* __restrict__ vtg, unsigned short* __restrict__ og) {
  __shared__ __align__(16) unsigned short Kl[2][64 * 128];
  __shared__ __align__(16) unsigned short Vtl[2][128 * 64];
  __shared__ __align__(16) unsigned short Plds[4][16 * 72];
  const int tid = threadIdx.x, l = tid & 63, w = tid >> 6;
  const int lg = l >> 4, li = l & 15;
  const int i0 = blockIdx.x * 64, hq = blockIdx.y;
  const int kv = hq >> 1;
  const int qr0 = i0 + w * 16;
  const float scale = 0.08838834764831845f;

  bf16x8 qf[4];
  {
    const unsigned short* qrow = qg + (size_t)(qr0 + li) * (NH * HD) + hq * HD;
    #pragma unroll
    for (int sl = 0; sl < 4; ++sl)
      qf[sl] = *(const bf16x8*)(qrow + sl * 32 + lg * 8);
  }
  f32x4 oacc[8] = {};
  float mrow[4] = {-1e30f, -1e30f, -1e30f, -1e30f};
  float srow[4] = {0.f, 0.f, 0.f, 0.f};

  int jstart = i0 - WIN; if (jstart < 0) jstart = 0;
  stageKV(kg, vtg, kv, jstart, Kl[0], Vtl[0], w, l);

  int it = 0;
  for (int j0 = jstart; j0 <= i0; j0 += 64, ++it) {
    const int cur = it & 1;
    asm volatile("s_waitcnt vmcnt(0) lgkmcnt(0)\n\ts_barrier" ::: "memory");
    if (j0 + 64 <= i0)
      stageKV(kg, vtg, kv, j0 + 64, Kl[cur ^ 1], Vtl[cur ^ 1], w, l);
    const unsigned short* Klds  = Kl[cur];
    const unsigned short* Vtlds = Vtl[cur];

    f32x4 sacc[4] = {};
    #pragma unroll
    for (int nt = 0; nt < 4; ++nt) {
      int kr = nt * 16 + li;
      #pragma unroll
      for (int sl = 0; sl < 4; ++sl) {
        int cb = (sl * 64 + lg * 16) ^ ((kr & 7) << 4);
        bf16x8 kf = *(const bf16x8*)&Klds[(kr * 256 + cb) >> 1];
        sacc[nt] = mfma16(qf[sl], kf, sacc[nt]);
      }
    }

    float pv[4][4];
    float sval[4][4], pmax[4];
    #pragma unroll
    for (int r = 0; r < 4; ++r) {
      int qi = qr0 + lg * 4 + r;
      float tm = -1e30f;
      #pragma unroll
      for (int nt = 0; nt < 4; ++nt) {
        int j = j0 + nt * 16 + li;
        bool ok = (j <= qi) && (j + WIN >= qi);
        float sv = ok ? sacc[nt][r] * scale : -1e30f;
        sval[r][nt] = sv;
        tm = fmaxf(tm, sv);
      }
      pmax[r] = tm;
    }
    bool cond = (pmax[0] - mrow[0] <= 8.f) && (pmax[1] - mrow[1] <= 8.f) &&
                (pmax[2] - mrow[2] <= 8.f) && (pmax[3] - mrow[3] <= 8.f);
    if (__all(cond)) {
      #pragma unroll
      for (int r = 0; r < 4; ++r) {
        float rs = 0.f;
        #pragma unroll
        for (int nt = 0; nt < 4; ++nt) {
          float p = (sval[r][nt] > -9e29f) ? __expf(sval[r][nt] - mrow[r]) : 0.f;
          pv[nt][r] = p;
          rs += p;
        }
        #pragma unroll
        for (int off2 = 1; off2 < 16; off2 <<= 1)
          rs += __shfl_xor(rs, off2, 64);
        srow[r] += rs;
      }
    } else {
      #pragma unroll
      for (int r = 0; r < 4; ++r) {
        float tm = pmax[r];
        #pragma unroll
        for (int off2 = 1; off2 < 16; off2 <<= 1)
          tm = fmaxf(tm, __shfl_xor(tm, off2, 64));
        float mnew = fmaxf(mrow[r], tm);
        float resc = __expf(mrow[r] - mnew);
        mrow[r] = mnew;
        float rs = 0.f;
        #pragma unroll
        for (int nt = 0; nt < 4; ++nt) {
          float p = (sval[r][nt] > -9e29f) ? __expf(sval[r][nt] - mnew) : 0.f;
          pv[nt][r] = p;
          rs += p;
        }
        #pragma unroll
        for (int off2 = 1; off2 < 16; off2 <<= 1)
          rs += __shfl_xor(rs, off2, 64);
        srow[r] = srow[r] * resc + rs;
        #pragma unroll
        for (int dt = 0; dt < 8; ++dt) oacc[dt][r] *= resc;
      }
    }

    #pragma unroll
    for (int r = 0; r < 4; ++r)
      #pragma unroll
      for (int nt = 0; nt < 4; ++nt)
        Plds[w][(lg * 4 + r) * 72 + nt * 16 + li] = f2b(pv[nt][r]);
    bf16x8 ap[2];
    #pragma unroll
    for (int ks = 0; ks < 2; ++ks)
      ap[ks] = *(const bf16x8*)&Plds[w][li * 72 + ks * 32 + lg * 8];
    #pragma unroll
    for (int dt = 0; dt < 8; ++dt) {
      int d = dt * 16 + li;
      #pragma unroll
      for (int ks = 0; ks < 2; ++ks) {
        int cb = (ks * 64 + lg * 16) ^ ((d & 7) << 4);
        bf16x8 vf = *(const bf16x8*)&Vtlds[(d * 128 + cb) >> 1];
        oacc[dt] = mfma16(ap[ks], vf, oacc[dt]);
      }
    }
  }

  #pragma unroll
  for (int r = 0; r < 4; ++r) {
    float inv = 1.0f / srow[r];
    int qi = qr0 + lg * 4 + r;
    unsigned short* orow = og + (size_t)qi * (NH * HD) + hq * HD;
    #pragma unroll
    for (int dt = 0; dt < 8; ++dt)
      orow[dt * 16 + li] = f2b(oacc[dt][r] * inv);
  }
}

// ---------------------------------------------------------------- launch
extern "C" void kernel_launch(void* const* d_in, const int* in_sizes, int n_in,
                              void* d_out, int out_size, void* d_ws, size_t ws_size,
                              hipStream_t stream) {
  const int*   ids   = (const int*)d_in[0];
  const float* embed = (const float*)d_in[1];
  const float* Wq    = (const float*)d_in[2];
  const float* Wk    = (const float*)d_in[3];
  const float* Wv    = (const float*)d_in[4];
  const float* Wo    = (const float*)d_in[5];
  const float* Wg    = (const float*)d_in[6];
  const float* Wu    = (const float*)d_in[7];
  const float* Wd    = (const float*)d_in[8];
  const float* ln1   = (const float*)d_in[9];
  const float* ln2   = (const float*)d_in[10];
  const float* normw = (const float*)d_in[11];

  uint8_t* ws = (uint8_t*)d_ws;
  unsigned short* wqkvT = (unsigned short*)(ws + 0);            // [4096][2048] bf16
  unsigned short* woT   = (unsigned short*)(ws + 16777216ull);  // [2048][2048]
  unsigned short* wguT  = (unsigned short*)(ws + 25165824ull);  // [11264][2048] packed G/U
  unsigned short* wdT   = (unsigned short*)(ws + 71303168ull);  // [2048][5632]
  float*          x     = (float*)(ws + 94371840ull);           // residual f32
  unsigned short* h     = (unsigned short*)(ws + 111149056ull); // rmsnorm out bf16
  unsigned short* q     = (unsigned short*)(ws + 119537664ull); // [S][16][128]
  unsigned short* k     = (unsigned short*)(ws + 127926272ull); // [S][8][128]
  unsigned short* vt    = (unsigned short*)(ws + 132120576ull); // [8][128][S]
  unsigned short* o     = (unsigned short*)(ws + 136314880ull); // [S][2048]
  unsigned short* act   = (unsigned short*)(ws + 119537664ull); // overlays q/k/vt/o (dead)
  unsigned short* pbuf  = (unsigned short*)(ws + 144703488ull); // bf16 K-split partials
  float*          cost  = (float*)(ws + 213909504ull);
  float*          sint  = (float*)(ws + 214433792ull);
  const long long PSel = 4194304LL;   // partial stride (2048*2048 elems bf16)

  gather_kernel<<<2048, 256, 0, stream>>>(ids, embed, x, cost, sint, ln1, h);

  for (int l = 0; l < 2; ++l) {
    convert_weights_kernel<<<5760, 256, 0, stream>>>(
        Wq + (size_t)l * 2048 * 2048, Wk + (size_t)l * 2048 * 1024,
        Wv + (size_t)l * 2048 * 1024, Wo + (size_t)l * 2048 * 2048,
        Wg + (size_t)l * 2048 * 5632, Wu + (size_t)l * 2048 * 5632,
        Wd + (size_t)l * 5632 * 2048,
        wqkvT, woT, wguT, wdT);
    if (l == 1)
      rmsnorm_combine_kernel<0, 2><<<2048, 256, 0, stream>>>(x, pbuf, ln1 + 2048, h);
    // QKV: 256 blocks, fused RoPE + V-transpose epilogue (writes q, k, vt)
    gemm128_kernel<4><<<256, 512, 0, stream>>>(h, wqkvT, q, 2048, 32, 1, 16, 2048, 0,
                                               cost, sint, k, vt);
    attn_kernel<<<dim3(32, 16), 256, 0, stream>>>(q, k, vt, o);
    // O-proj: 128 tiles x splitK2 = 256 blocks, bf16 partials
    gemm128_kernel<0><<<256, 512, 0, stream>>>(o, woT, pbuf, 2048, 16, 2, 16, 2048, PSel,
                                               nullptr, nullptr, nullptr, nullptr);
    rmsnorm_combine_kernel<0, 2><<<2048, 256, 0, stream>>>(x, pbuf, ln2 + l * 2048, h);
    // gate/up fused silu: 16x44 = 704 blocks (4-phase 128x256, 92% packing)
    gemm128_kernel<3><<<704, 512, 0, stream>>>(h, wguT, act, 2048, 32, 1, 16, 5632, 0,
                                               nullptr, nullptr, nullptr, nullptr);
    // down: 128 tiles x splitK2 = 256 blocks, bf16 partials
    gemm128_kernel<0><<<256, 512, 0, stream>>>(act, wdT, pbuf, 5632, 44, 2, 16, 2048, PSel,
                                               nullptr, nullptr, nullptr, nullptr);
  }
  rmsnorm_combine_kernel<1, 2><<<2048, 256, 0, stream>>>(x, pbuf, normw, d_out);
  (void)in_sizes; (void)n_in; (void)out_size; (void)ws_size;
}

// Round 14
// 664.612 us; speedup vs baseline: 1.0164x; 1.0164x over previous
//
#include <hip/hip_runtime.h>
#include <stdint.h>

using bf16x8 = __attribute__((ext_vector_type(8))) __bf16;
using f32x4  = __attribute__((ext_vector_type(4))) float;

#define DEVI __device__ __forceinline__

DEVI unsigned short f2b(float f) {
  unsigned int u = __builtin_bit_cast(unsigned int, f);
  u = (u + 0x7FFFu + ((u >> 16) & 1u)) >> 16;
  return (unsigned short)u;
}
DEVI float b2f(unsigned short h) {
  unsigned int u = ((unsigned int)h) << 16;
  return __builtin_bit_cast(float, u);
}
DEVI f32x4 mfma16(bf16x8 a, bf16x8 b, f32x4 c) {
  return __builtin_amdgcn_mfma_f32_16x16x32_bf16(a, b, c, 0, 0, 0);
}
#define GLD(gp, lp) __builtin_amdgcn_global_load_lds( \
    (__attribute__((address_space(1))) void*)(uintptr_t)(gp), \
    (__attribute__((address_space(3))) void*)(uintptr_t)(lp), 16, 0, 0)

static constexpr int S_LEN = 2048;
static constexpr int HDIM  = 2048;
static constexpr int NH    = 16;
static constexpr int NKV   = 8;
static constexpr int HD    = 128;
static constexpr int IFF   = 5632;
static constexpr int WIN   = 1024;

// ---------------------------------------------------------------- RMSNorm core
DEVI void rms_finish(float4 v0, float4 v1, const float* __restrict__ w,
                     void* __restrict__ outp, int s, int t, int outf32) {
  float ss = v0.x*v0.x + v0.y*v0.y + v0.z*v0.z + v0.w*v0.w +
             v1.x*v1.x + v1.y*v1.y + v1.z*v1.z + v1.w*v1.w;
  #pragma unroll
  for (int off = 32; off >= 1; off >>= 1) ss += __shfl_xor(ss, off, 64);
  __shared__ float red[4];
  if ((t & 63) == 0) red[t >> 6] = ss;
  __syncthreads();
  ss = red[0] + red[1] + red[2] + red[3];
  float rr = rsqrtf(ss * (1.0f / 2048.0f) + 1e-6f);
  const float4* w4 = (const float4*)w;
  float4 w0 = w4[t], w1 = w4[t + 256];
  float o0x = v0.x*rr*w0.x, o0y = v0.y*rr*w0.y, o0z = v0.z*rr*w0.z, o0w = v0.w*rr*w0.w;
  float o1x = v1.x*rr*w1.x, o1y = v1.y*rr*w1.y, o1z = v1.z*rr*w1.z, o1w = v1.w*rr*w1.w;
  if (outf32) {
    float4* o4 = (float4*)outp + (size_t)s * 512;
    o4[t]       = make_float4(o0x, o0y, o0z, o0w);
    o4[t + 256] = make_float4(o1x, o1y, o1z, o1w);
  } else {
    uint2* ob = (uint2*)((unsigned short*)outp + (size_t)s * HDIM);
    ob[t]       = make_uint2((unsigned)f2b(o0x) | ((unsigned)f2b(o0y) << 16),
                             (unsigned)f2b(o0z) | ((unsigned)f2b(o0w) << 16));
    ob[t + 256] = make_uint2((unsigned)f2b(o1x) | ((unsigned)f2b(o1y) << 16),
                             (unsigned)f2b(o1z) | ((unsigned)f2b(o1w) << 16));
  }
}

// ---------------------------------------------------------------- gather + rope tables + layer0 ln1
__global__ __launch_bounds__(256) void gather_kernel(const int* __restrict__ ids,
    const float* __restrict__ embed, float* __restrict__ x,
    float* __restrict__ ct, float* __restrict__ st,
    const float* __restrict__ ln1w, unsigned short* __restrict__ h) {
  int s = blockIdx.x, t = threadIdx.x;
  const float4* src = (const float4*)(embed + (size_t)ids[s] * HDIM);
  float4* dst = (float4*)(x + (size_t)s * HDIM);
  float4 v0 = src[t], v1 = src[t + 256];
  dst[t]       = v0;
  dst[t + 256] = v1;
  if (t < 64) {
    float inv = expf(-(float)t * (9.210340371976184f / 64.0f));  // theta^(-t/64)
    float f = (float)s * inv;
    ct[s * 64 + t] = cosf(f);
    st[s * 64 + t] = sinf(f);
  }
  rms_finish(v0, v1, ln1w, h, s, t, 0);   // layer-0 ln1 output (bf16)
}

// x += sum of NPARTS K-split partials (bf16, fixed order), then norm.
template<int OUTF32, int NPARTS>
__global__ __launch_bounds__(256) void rmsnorm_combine_kernel(
    float* __restrict__ x, const unsigned short* __restrict__ parts,
    const float* __restrict__ w, void* __restrict__ outp) {
  int s = blockIdx.x, t = threadIdx.x;
  const size_t PS = (size_t)2048 * 2048;
  float4* row = (float4*)(x + (size_t)s * HDIM);
  float4 v0 = row[t], v1 = row[t + 256];
  #pragma unroll
  for (int p = 0; p < NPARTS; ++p) {
    const unsigned short* pr = parts + p * PS + (size_t)s * HDIM;
    uint2 a = *(const uint2*)(pr + t * 4);
    uint2 b = *(const uint2*)(pr + (t + 256) * 4);
    v0.x += b2f((unsigned short)a.x); v0.y += b2f((unsigned short)(a.x >> 16));
    v0.z += b2f((unsigned short)a.y); v0.w += b2f((unsigned short)(a.y >> 16));
    v1.x += b2f((unsigned short)b.x); v1.y += b2f((unsigned short)(b.x >> 16));
    v1.z += b2f((unsigned short)b.y); v1.w += b2f((unsigned short)(b.y >> 16));
  }
  row[t] = v0; row[t + 256] = v1;
  rms_finish(v0, v1, w, outp, s, t, OUTF32);
}

// ---------------------------------------------------------------- weight transpose+cvt
// [128 k][64 n] input tiles -> out[n][k] bf16, packed u32 stores.
// Wg/Wu packed interleaved by 128-feature blocks (for fused silu epilogue).
__global__ __launch_bounds__(256) void convert_weights_kernel(
    const float* __restrict__ Wq, const float* __restrict__ Wk,
    const float* __restrict__ Wv, const float* __restrict__ Wo,
    const float* __restrict__ Wg, const float* __restrict__ Wu,
    const float* __restrict__ Wd,
    unsigned short* wqkvT, unsigned short* woT,
    unsigned short* wguT, unsigned short* wdT) {
  __shared__ float tl[128 * 65];
  int b = blockIdx.x;
  const float* in; unsigned short* out; int istr, ostr, tilesN, t; int guAdd = -1;
  if (b < 512)       { in = Wq; out = wqkvT;                       istr = 2048; ostr = 2048; tilesN = 32; t = b; }
  else if (b < 768)  { in = Wk; out = wqkvT + (size_t)2048 * 2048; istr = 1024; ostr = 2048; tilesN = 16; t = b - 512; }
  else if (b < 1024) { in = Wv; out = wqkvT + (size_t)3072 * 2048; istr = 1024; ostr = 2048; tilesN = 16; t = b - 768; }
  else if (b < 1536) { in = Wo; out = woT;                         istr = 2048; ostr = 2048; tilesN = 32; t = b - 1024; }
  else if (b < 2944) { in = Wg; out = wguT;                        istr = 5632; ostr = 2048; tilesN = 88; t = b - 1536; guAdd = 0; }
  else if (b < 4352) { in = Wu; out = wguT;                        istr = 5632; ostr = 2048; tilesN = 88; t = b - 2944; guAdd = 128; }
  else               { in = Wd; out = wdT;                         istr = 2048; ostr = 5632; tilesN = 32; t = b - 4352; }
  int k0 = (t / tilesN) * 128, n0 = (t % tilesN) * 64;
  int tx = threadIdx.x & 63, ty = threadIdx.x >> 6;
  #pragma unroll
  for (int i = 0; i < 32; ++i)
    tl[(ty + 4 * i) * 65 + tx] = in[(size_t)(k0 + ty + 4 * i) * istr + (n0 + tx)];
  __syncthreads();
  int ob = (guAdd >= 0) ? (((n0 >> 7) << 8) + (n0 & 64) + guAdd) : n0;
  unsigned int* ou = (unsigned int*)out;
  const int kstr2 = ostr >> 1;
  #pragma unroll
  for (int i = 0; i < 16; ++i) {
    int nrow = ty + 4 * i;
    float lo = tl[(2 * tx) * 65 + nrow], hi = tl[(2 * tx + 1) * 65 + nrow];
    ou[(size_t)(ob + nrow) * kstr2 + (k0 >> 1) + tx] =
        (unsigned int)f2b(lo) | ((unsigned int)f2b(hi) << 16);
  }
}

// ---------------------------------------------------------------- shared GEMM helpers
DEVI bf16x8 ldsAB(const unsigned short* buf, int r, int cbyte) {
  return *(const bf16x8*)((const unsigned char*)buf + r * 128 + (cbyte ^ ((r & 7) << 4)));
}
DEVI void stage_unit(const unsigned short* __restrict__ G, int Kstr,
                     unsigned short* lbuf, int loff0, int grow0,
                     int loff1, int grow1, int w, int l) {
  const int rsub = l >> 3;
  const int ce = ((l & 7) ^ rsub) << 3;           // pre-swizzled source col
  const unsigned short* s0 = G + (size_t)(grow0 + w * 8 + rsub) * Kstr + ce;
  GLD(s0, (unsigned char*)lbuf + loff0 + w * 1024 + l * 16);
  const unsigned short* s1 = G + (size_t)(grow1 + w * 8 + rsub) * Kstr + ce;
  GLD(s1, (unsigned char*)lbuf + loff1 + w * 1024 + l * 16);
}

// ---------------------------------------------------------------- 128x256 deep-pipelined GEMM (R10-proven best)
// 8 waves (2Mx4N), BK=64. ONE barrier per K-tile, race-free by construction:
// B is TRIPLE-buffered (slot = k mod 3, rotating pointers), A double (parity).
template<int Q>
DEVI void phase128(const unsigned short* Ab, f32x4 (&acc)[4][4],
                   bf16x8 (&breg)[2][4], int wr, int lg, int li) {
  const int r0 = wr * 64 + Q * 16 + li;
  bf16x8 a0 = ldsAB(Ab, r0, lg * 16);
  bf16x8 a1 = ldsAB(Ab, r0, 64 + lg * 16);
  __builtin_amdgcn_s_setprio(1);
  #pragma unroll
  for (int n = 0; n < 4; ++n) acc[Q][n] = mfma16(a0, breg[0][n], acc[Q][n]);
  #pragma unroll
  for (int n = 0; n < 4; ++n) acc[Q][n] = mfma16(a1, breg[1][n], acc[Q][n]);
  __builtin_amdgcn_s_setprio(0);
}

// EPI: 0 = bf16 partial store; 3 = fused silu(g)*u; 4 = qkv epilogue
template<int EPI>
__global__ __launch_bounds__(512, 1) void gemm128_kernel(
    const unsigned short* __restrict__ A, const unsigned short* __restrict__ Bt,
    void* __restrict__ Cout, int Kstr, int nt, int parts, int nbm, int ldc,
    long long partStride,
    const float* __restrict__ ct, const float* __restrict__ st,
    unsigned short* __restrict__ ko, unsigned short* __restrict__ vt) {
  __shared__ __align__(16) unsigned char smem[131072];
  unsigned short* As0 = (unsigned short*)smem;             // [2][128*64] elems (16KB each)
  unsigned short* Bs0 = (unsigned short*)(smem + 32768);   // [3][256*64] elems (32KB each)
  const int tid = threadIdx.x, l = tid & 63, w = tid >> 6;
  const int lg = l >> 4, li = l & 15;
  const int wr = w >> 2, wc = w & 3;
  const int nb = gridDim.x, qx = nb >> 3;
  const int wg = ((int)blockIdx.x & 7) * qx + ((int)blockIdx.x >> 3);  // XCD swizzle (nb%8==0)
  const int nbT = nb / parts;
  const int tile = wg % nbT, part = wg / nbT;
  const int m0 = (tile % nbm) * 128, n0 = (tile / nbm) * 256;  // column-major: B-panel L2 reuse
  const int kOff = part * (nt << 6);
  const unsigned short* At  = A  + (size_t)m0 * Kstr + kOff;
  const unsigned short* Bto = Bt + (size_t)n0 * Kstr + kOff;
  f32x4 acc[4][4] = {};
  bf16x8 breg[2][4];
  unsigned short* B0p = Bs0;                // holds B(t)   (read slot)
  unsigned short* B1p = Bs0 + 16384;        // holds B(t+1)
  unsigned short* B2p = Bs0 + 32768;        // stage target B(t+2)

  // prologue: B(0)x4, A(0)x2, B(1)x4 -> vmcnt(4) retires B(0)+A(0); barrier publishes
  stage_unit(Bto, Kstr, B0p, 0, 0, 8192, 64, w, l);
  stage_unit(Bto, Kstr, B0p, 16384, 128, 24576, 192, w, l);
  stage_unit(At,  Kstr, As0, 0, 0, 8192, 64, w, l);
  { int k1 = (nt > 1) ? 64 : 0;
    stage_unit(Bto + k1, Kstr, B1p, 0, 0, 8192, 64, w, l);
    stage_unit(Bto + k1, Kstr, B1p, 16384, 128, 24576, 192, w, l); }
  asm volatile("s_waitcnt vmcnt(4)\n\ts_barrier" ::: "memory");

  for (int t = 0; t < nt; ++t) {
    unsigned short* Ab  = As0 + (t & 1) * 8192;
    unsigned short* Abn = As0 + ((t & 1) ^ 1) * 8192;
    const int kt1 = ((t + 1 < nt) ? t + 1 : nt - 1) << 6;   // clamped tail keeps queue uniform
    const int kt2 = ((t + 2 < nt) ? t + 2 : nt - 1) << 6;
    // ph0: stage A(t+1) -> other A slot; breg(t) from B0p (published last barrier)
    stage_unit(At + kt1, Kstr, Abn, 0, 0, 8192, 64, w, l);
    #pragma unroll
    for (int ks = 0; ks < 2; ++ks)
      #pragma unroll
      for (int n = 0; n < 4; ++n)
        breg[ks][n] = ldsAB(B0p, wc * 64 + n * 16 + li, ks * 64 + lg * 16);
    phase128<0>(Ab, acc, breg, wr, lg, li);
    // ph1: stage B0(t+2) -> B2p (dead slot; no read conflict this tile)
    stage_unit(Bto + kt2, Kstr, B2p, 0, 0, 8192, 64, w, l);
    phase128<1>(Ab, acc, breg, wr, lg, li);
    // ph2: stage B1(t+2) -> B2p
    stage_unit(Bto + kt2, Kstr, B2p, 16384, 128, 24576, 192, w, l);
    phase128<2>(Ab, acc, breg, wr, lg, li);
    // ph3
    phase128<3>(Ab, acc, breg, wr, lg, li);
    // single per-tile sync: retires B(t+1)+A(t+1) in every wave, then publishes
    asm volatile("s_waitcnt vmcnt(4) lgkmcnt(0)\n\ts_barrier" ::: "memory");
    unsigned short* tmp = B0p; B0p = B1p; B1p = B2p; B2p = tmp;
  }
  asm volatile("s_waitcnt vmcnt(0)" ::: "memory");

  if (EPI == 0) {
    unsigned short* C = (unsigned short*)Cout + (size_t)part * (size_t)partStride;
    #pragma unroll
    for (int m = 0; m < 4; ++m)
      #pragma unroll
      for (int n = 0; n < 4; ++n) {
        int col = n0 + wc * 64 + n * 16 + li;
        #pragma unroll
        for (int r = 0; r < 4; ++r) {
          int row = m0 + wr * 64 + m * 16 + lg * 4 + r;
          C[(size_t)row * ldc + col] = f2b(acc[m][n][r]);
        }
      }
  } else if (EPI == 3) {
    // fused silu: tile cols [0,128) = G features, [128,256) = matching U.
    float* ub = (float*)smem;   // [128][128] f32 = 64KB (LDS reuse after drain)
    asm volatile("s_barrier" ::: "memory");
    if (wc >= 2) {
      #pragma unroll
      for (int m = 0; m < 4; ++m)
        #pragma unroll
        for (int n = 0; n < 4; ++n) {
          int colL = (wc - 2) * 64 + n * 16 + li;
          #pragma unroll
          for (int r = 0; r < 4; ++r) {
            int rowl = wr * 64 + m * 16 + lg * 4 + r;
            ub[rowl * 128 + colL] = acc[m][n][r];
          }
        }
    }
    asm volatile("s_waitcnt lgkmcnt(0)\n\ts_barrier" ::: "memory");
    if (wc < 2) {
      unsigned short* act = (unsigned short*)Cout;
      const int col0 = n0 >> 1;
      #pragma unroll
      for (int m = 0; m < 4; ++m)
        #pragma unroll
        for (int n = 0; n < 4; ++n) {
          int colL = wc * 64 + n * 16 + li;
          #pragma unroll
          for (int r = 0; r < 4; ++r) {
            int rowl = wr * 64 + m * 16 + lg * 4 + r;
            float g = acc[m][n][r];
            float u = ub[rowl * 128 + colL];
            act[(size_t)(m0 + rowl) * ldc + col0 + colL] =
                f2b(g / (1.0f + __expf(-g)) * u);
          }
        }
    }
  } else {
    // EPI == 4: qkv epilogue. Dump acc to LDS f32 [128][256], then per region:
    // Q/K: RoPE with partner at colL^64 -> bf16. V: transposed write to vt[d][s].
    float* dump = (float*)smem;
    asm volatile("s_barrier" ::: "memory");       // all waves drained vmcnt(0)
    #pragma unroll
    for (int m = 0; m < 4; ++m)
      #pragma unroll
      for (int n = 0; n < 4; ++n) {
        int colL = wc * 64 + n * 16 + li;
        #pragma unroll
        for (int r = 0; r < 4; ++r) {
          int rowl = wr * 64 + m * 16 + lg * 4 + r;
          dump[rowl * 256 + colL] = acc[m][n][r];
        }
      }
    asm volatile("s_waitcnt lgkmcnt(0)\n\ts_barrier" ::: "memory");
    if (n0 < 3072) {
      unsigned short* qk = (n0 < 2048) ? (unsigned short*)Cout : ko;
      const int cbase = (n0 < 2048) ? n0 : (n0 - 2048);
      const int ostr  = (n0 < 2048) ? 2048 : 1024;
      #pragma unroll
      for (int m = 0; m < 4; ++m)
        #pragma unroll
        for (int n = 0; n < 4; ++n) {
          int colL = wc * 64 + n * 16 + li;
          int hi = colL & 64;
          #pragma unroll
          for (int r = 0; r < 4; ++r) {
            int rowl = wr * 64 + m * 16 + lg * 4 + r;
            int s = m0 + rowl;
            float own = dump[rowl * 256 + colL];
            float par = dump[rowl * 256 + (colL ^ 64)];
            float c  = ct[s * 64 + (colL & 63)];
            float sn = st[s * 64 + (colL & 63)];
            float v = hi ? (own * c + par * sn) : (own * c - par * sn);
            qk[(size_t)s * ostr + cbase + colL] = f2b(v);
          }
        }
    } else {
      // 512 threads -> 256 vcols x 2 s-halves; 64 bf16 (128B) contiguous per thread
      int vcol = tid >> 1, sh = (tid & 1) * 64;
      unsigned short* dstp = vt + (size_t)(n0 - 3072 + vcol) * 2048 + m0 + sh;
      #pragma unroll
      for (int c8 = 0; c8 < 8; ++c8) {
        unsigned short pk[8];
        #pragma unroll
        for (int i = 0; i < 8; ++i)
          pk[i] = f2b(dump[(sh + c8 * 8 + i) * 256 + vcol]);
        *(uint4*)(dstp + c8 * 8) = *(const uint4*)pk;
      }
    }
  }
}

// ---------------------------------------------------------------- sliding-window flash attention v2 + T13 defer-max
// block = (q-tile 64, kv-head); 8 waves: w0-3 -> head 2kv, w4-7 -> head 2kv+1.
// K/V staged once per pair, double-buffered (stage next before compute).
DEVI void stageKV(const unsigned short* __restrict__ kg,
                  const unsigned short* __restrict__ vtg, int kv, int j0,
                  unsigned short* Kbuf, unsigned short* Vbuf, int w, int l) {
  #pragma unroll
  for (int p = 0; p < 2; ++p) {
    int off = p * 8192 + w * 1024 + l * 16;
    int row = off >> 8;
    int colb = (off & 255) ^ ((row & 7) << 4);
    GLD(kg + (size_t)(j0 + row) * (NKV * HD) + kv * HD + (colb >> 1),
        (unsigned char*)Kbuf + off);
  }
  #pragma unroll
  for (int p = 0; p < 2; ++p) {
    int off = p * 8192 + w * 1024 + l * 16;
    int d = off >> 7;
    int colb = (off & 127) ^ ((d & 7) << 4);
    GLD(vtg + (size_t)(kv * HD + d) * S_LEN + j0 + (colb >> 1),
        (unsigned char*)Vbuf + off);
  }
}

__global__ __launch_bounds__(512) void attn_kernel(
    const unsigned short* __restrict__ qg, const unsigned short* __restrict__ kg,
    const unsigned short* __restrict__ vtg, unsigned short* __restrict__ og) {
  __shared__ __align__(16) unsigned short Kl[2][64 * 128];
  __shared__ __align__(16) unsigned short Vtl[2][128 * 64];
  __shared__ __align__(16) unsigned short Plds[8][16 * 72];
  const int tid = threadIdx.x, l = tid & 63, w = tid >> 6;
  const int lg = l >> 4, li = l & 15;
  const int i0 = blockIdx.x * 64, kv = blockIdx.y;
  const int hq = kv * 2 + (w >> 2);
  const int qr0 = i0 + (w & 3) * 16;
  const float scale = 0.08838834764831845f;

  bf16x8 qf[4];
  {
    const unsigned short* qrow = qg + (size_t)(qr0 + li) * (NH * HD) + hq * HD;
    #pragma unroll
    for (int sl = 0; sl < 4; ++sl)
      qf[sl] = *(const bf16x8*)(qrow + sl * 32 + lg * 8);
  }
  f32x4 oacc[8] = {};
  float mrow[4] = {-1e30f, -1e30f, -1e30f, -1e30f};
  float srow[4] = {0.f, 0.f, 0.f, 0.f};

  int jstart = i0 - WIN; if (jstart < 0) jstart = 0;
  stageKV(kg, vtg, kv, jstart, Kl[0], Vtl[0], w, l);

  int it = 0;
  for (int j0 = jstart; j0 <= i0; j0 += 64, ++it) {
    const int cur = it & 1;
    asm volatile("s_waitcnt vmcnt(0) lgkmcnt(0)\n\ts_barrier" ::: "memory");
    if (j0 + 64 <= i0)
      stageKV(kg, vtg, kv, j0 + 64, Kl[cur ^ 1], Vtl[cur ^ 1], w, l);
    const unsigned short* Klds  = Kl[cur];
    const unsigned short* Vtlds = Vtl[cur];

    f32x4 sacc[4] = {};
    #pragma unroll
    for (int nt = 0; nt < 4; ++nt) {
      int kr = nt * 16 + li;
      #pragma unroll
      for (int sl = 0; sl < 4; ++sl) {
        int cb = (sl * 64 + lg * 16) ^ ((kr & 7) << 4);
        bf16x8 kf = *(const bf16x8*)&Klds[(kr * 256 + cb) >> 1];
        sacc[nt] = mfma16(qf[sl], kf, sacc[nt]);
      }
    }

    float pv[4][4];
    float sval[4][4], pmax[4];
    #pragma unroll
    for (int r = 0; r < 4; ++r) {
      int qi = qr0 + lg * 4 + r;
      float tm = -1e30f;
      #pragma unroll
      for (int nt = 0; nt < 4; ++nt) {
        int j = j0 + nt * 16 + li;
        bool ok = (j <= qi) && (j + WIN >= qi);
        float sv = ok ? sacc[nt][r] * scale : -1e30f;
        sval[r][nt] = sv;
        tm = fmaxf(tm, sv);
      }
      pmax[r] = tm;
    }
    // T13 defer-max: skip max-reduce + rescale when growth bounded (P <= e^8)
    bool cond = (pmax[0] - mrow[0] <= 8.f) && (pmax[1] - mrow[1] <= 8.f) &&
                (pmax[2] - mrow[2] <= 8.f) && (pmax[3] - mrow[3] <= 8.f);
    if (__all(cond)) {
      #pragma unroll
      for (int r = 0; r < 4; ++r) {
        float rs = 0.f;
        #pragma unroll
        for (int nt = 0; nt < 4; ++nt) {
          float p = (sval[r][nt] > -9e29f) ? __expf(sval[r][nt] - mrow[r]) : 0.f;
          pv[nt][r] = p;
          rs += p;
        }
        #pragma unroll
        for (int off2 = 1; off2 < 16; off2 <<= 1)
          rs += __shfl_xor(rs, off2, 64);
        srow[r] += rs;
      }
    } else {
      #pragma unroll
      for (int r = 0; r < 4; ++r) {
        float tm = pmax[r];
        #pragma unroll
        for (int off2 = 1; off2 < 16; off2 <<= 1)
          tm = fmaxf(tm, __shfl_xor(tm, off2, 64));
        float mnew = fmaxf(mrow[r], tm);
        float resc = __expf(mrow[r] - mnew);
        mrow[r] = mnew;
        float rs = 0.f;
        #pragma unroll
        for (int nt = 0; nt < 4; ++nt) {
          float p = (sval[r][nt] > -9e29f) ? __expf(sval[r][nt] - mnew) : 0.f;
          pv[nt][r] = p;
          rs += p;
        }
        #pragma unroll
        for (int off2 = 1; off2 < 16; off2 <<= 1)
          rs += __shfl_xor(rs, off2, 64);
        srow[r] = srow[r] * resc + rs;
        #pragma unroll
        for (int dt = 0; dt < 8; ++dt) oacc[dt][r] *= resc;
      }
    }

    #pragma unroll
    for (int r = 0; r < 4; ++r)
      #pragma unroll
      for (int nt = 0; nt < 4; ++nt)
        Plds[w][(lg * 4 + r) * 72 + nt * 16 + li] = f2b(pv[nt][r]);
    bf16x8 ap[2];
    #pragma unroll
    for (int ks = 0; ks < 2; ++ks)
      ap[ks] = *(const bf16x8*)&Plds[w][li * 72 + ks * 32 + lg * 8];
    #pragma unroll
    for (int dt = 0; dt < 8; ++dt) {
      int d = dt * 16 + li;
      #pragma unroll
      for (int ks = 0; ks < 2; ++ks) {
        int cb = (ks * 64 + lg * 16) ^ ((d & 7) << 4);
        bf16x8 vf = *(const bf16x8*)&Vtlds[(d * 128 + cb) >> 1];
        oacc[dt] = mfma16(ap[ks], vf, oacc[dt]);
      }
    }
  }

  #pragma unroll
  for (int r = 0; r < 4; ++r) {
    float inv = 1.0f / srow[r];
    int qi = qr0 + lg * 4 + r;
    unsigned short* orow = og + (size_t)qi * (NH * HD) + hq * HD;
    #pragma unroll
    for (int dt = 0; dt < 8; ++dt)
      orow[dt * 16 + li] = f2b(oacc[dt][r] * inv);
  }
}

// ---------------------------------------------------------------- launch
extern "C" void kernel_launch(void* const* d_in, const int* in_sizes, int n_in,
                              void* d_out, int out_size, void* d_ws, size_t ws_size,
                              hipStream_t stream) {
  const int*   ids   = (const int*)d_in[0];
  const float* embed = (const float*)d_in[1];
  const float* Wq    = (const float*)d_in[2];
  const float* Wk    = (const float*)d_in[3];
  const float* Wv    = (const float*)d_in[4];
  const float* Wo    = (const float*)d_in[5];
  const float* Wg    = (const float*)d_in[6];
  const float* Wu    = (const float*)d_in[7];
  const float* Wd    = (const float*)d_in[8];
  const float* ln1   = (const float*)d_in[9];
  const float* ln2   = (const float*)d_in[10];
  const float* normw = (const float*)d_in[11];

  uint8_t* ws = (uint8_t*)d_ws;
  unsigned short* wqkvT = (unsigned short*)(ws + 0);            // [4096][2048] bf16
  unsigned short* woT   = (unsigned short*)(ws + 16777216ull);  // [2048][2048]
  unsigned short* wguT  = (unsigned short*)(ws + 25165824ull);  // [11264][2048] packed G/U
  unsigned short* wdT   = (unsigned short*)(ws + 71303168ull);  // [2048][5632]
  float*          x     = (float*)(ws + 94371840ull);           // residual f32
  unsigned short* h     = (unsigned short*)(ws + 111149056ull); // rmsnorm out bf16
  unsigned short* q     = (unsigned short*)(ws + 119537664ull); // [S][16][128]
  unsigned short* k     = (unsigned short*)(ws + 127926272ull); // [S][8][128]
  unsigned short* vt    = (unsigned short*)(ws + 132120576ull); // [8][128][S]
  unsigned short* o     = (unsigned short*)(ws + 136314880ull); // [S][2048]
  unsigned short* act   = (unsigned short*)(ws + 119537664ull); // overlays q/k/vt/o (dead)
  unsigned short* pbuf  = (unsigned short*)(ws + 144703488ull); // bf16 K-split partials
  float*          cost  = (float*)(ws + 213909504ull);
  float*          sint  = (float*)(ws + 214433792ull);
  const long long PSel = 4194304LL;   // partial stride (2048*2048 elems bf16)

  gather_kernel<<<2048, 256, 0, stream>>>(ids, embed, x, cost, sint, ln1, h);

  for (int l = 0; l < 2; ++l) {
    convert_weights_kernel<<<5760, 256, 0, stream>>>(
        Wq + (size_t)l * 2048 * 2048, Wk + (size_t)l * 2048 * 1024,
        Wv + (size_t)l * 2048 * 1024, Wo + (size_t)l * 2048 * 2048,
        Wg + (size_t)l * 2048 * 5632, Wu + (size_t)l * 2048 * 5632,
        Wd + (size_t)l * 5632 * 2048,
        wqkvT, woT, wguT, wdT);
    if (l == 1)
      rmsnorm_combine_kernel<0, 2><<<2048, 256, 0, stream>>>(x, pbuf, ln1 + 2048, h);
    // QKV: 256 blocks, fused RoPE + V-transpose epilogue (writes q, k, vt)
    gemm128_kernel<4><<<256, 512, 0, stream>>>(h, wqkvT, q, 2048, 32, 1, 16, 2048, 0,
                                               cost, sint, k, vt);
    attn_kernel<<<dim3(32, 8), 512, 0, stream>>>(q, k, vt, o);
    // O-proj: 128 tiles x splitK2 = 256 blocks, bf16 partials
    gemm128_kernel<0><<<256, 512, 0, stream>>>(o, woT, pbuf, 2048, 16, 2, 16, 2048, PSel,
                                               nullptr, nullptr, nullptr, nullptr);
    rmsnorm_combine_kernel<0, 2><<<2048, 256, 0, stream>>>(x, pbuf, ln2 + l * 2048, h);
    // gate/up fused silu: 16x44 = 704 blocks (4-phase 128x256, 92% packing)
    gemm128_kernel<3><<<704, 512, 0, stream>>>(h, wguT, act, 2048, 32, 1, 16, 5632, 0,
                                               nullptr, nullptr, nullptr, nullptr);
    // down: 128 tiles x splitK2 = 256 blocks, bf16 partials
    gemm128_kernel<0><<<256, 512, 0, stream>>>(act, wdT, pbuf, 5632, 44, 2, 16, 2048, PSel,
                                               nullptr, nullptr, nullptr, nullptr);
  }
  rmsnorm_combine_kernel<1, 2><<<2048, 256, 0, stream>>>(x, pbuf, normw, d_out);
  (void)in_sizes; (void)n_in; (void)out_size; (void)ws_size;
}

// Round 15
// 649.656 us; speedup vs baseline: 1.0398x; 1.0230x over previous
//
#include <hip/hip_runtime.h>
#include <stdint.h>

using bf16x8 = __attribute__((ext_vector_type(8))) __bf16;
using f32x4  = __attribute__((ext_vector_type(4))) float;

#define DEVI __device__ __forceinline__

DEVI unsigned short f2b(float f) {
  unsigned int u = __builtin_bit_cast(unsigned int, f);
  u = (u + 0x7FFFu + ((u >> 16) & 1u)) >> 16;
  return (unsigned short)u;
}
DEVI float b2f(unsigned short h) {
  unsigned int u = ((unsigned int)h) << 16;
  return __builtin_bit_cast(float, u);
}
DEVI unsigned pk2(float a, float b) {
  return (unsigned)f2b(a) | ((unsigned)f2b(b) << 16);
}
DEVI f32x4 mfma16(bf16x8 a, bf16x8 b, f32x4 c) {
  return __builtin_amdgcn_mfma_f32_16x16x32_bf16(a, b, c, 0, 0, 0);
}
#define GLD(gp, lp) __builtin_amdgcn_global_load_lds( \
    (__attribute__((address_space(1))) void*)(uintptr_t)(gp), \
    (__attribute__((address_space(3))) void*)(uintptr_t)(lp), 16, 0, 0)

static constexpr int S_LEN = 2048;
static constexpr int HDIM  = 2048;
static constexpr int NH    = 16;
static constexpr int NKV   = 8;
static constexpr int HD    = 128;
static constexpr int IFF   = 5632;
static constexpr int WIN   = 1024;

// ---------------------------------------------------------------- RMSNorm core
DEVI void rms_finish(float4 v0, float4 v1, const float* __restrict__ w,
                     void* __restrict__ outp, int s, int t, int outf32) {
  float ss = v0.x*v0.x + v0.y*v0.y + v0.z*v0.z + v0.w*v0.w +
             v1.x*v1.x + v1.y*v1.y + v1.z*v1.z + v1.w*v1.w;
  #pragma unroll
  for (int off = 32; off >= 1; off >>= 1) ss += __shfl_xor(ss, off, 64);
  __shared__ float red[4];
  if ((t & 63) == 0) red[t >> 6] = ss;
  __syncthreads();
  ss = red[0] + red[1] + red[2] + red[3];
  float rr = rsqrtf(ss * (1.0f / 2048.0f) + 1e-6f);
  const float4* w4 = (const float4*)w;
  float4 w0 = w4[t], w1 = w4[t + 256];
  float o0x = v0.x*rr*w0.x, o0y = v0.y*rr*w0.y, o0z = v0.z*rr*w0.z, o0w = v0.w*rr*w0.w;
  float o1x = v1.x*rr*w1.x, o1y = v1.y*rr*w1.y, o1z = v1.z*rr*w1.z, o1w = v1.w*rr*w1.w;
  if (outf32) {
    float4* o4 = (float4*)outp + (size_t)s * 512;
    o4[t]       = make_float4(o0x, o0y, o0z, o0w);
    o4[t + 256] = make_float4(o1x, o1y, o1z, o1w);
  } else {
    uint2* ob = (uint2*)((unsigned short*)outp + (size_t)s * HDIM);
    ob[t]       = make_uint2(pk2(o0x, o0y), pk2(o0z, o0w));
    ob[t + 256] = make_uint2(pk2(o1x, o1y), pk2(o1z, o1w));
  }
}

// ---------------------------------------------------------------- gather + rope tables + layer0 ln1
// residual x stored bf16 (compute stays f32 in regs)
__global__ __launch_bounds__(256) void gather_kernel(const int* __restrict__ ids,
    const float* __restrict__ embed, unsigned short* __restrict__ x,
    float* __restrict__ ct, float* __restrict__ st,
    const float* __restrict__ ln1w, unsigned short* __restrict__ h) {
  int s = blockIdx.x, t = threadIdx.x;
  const float4* src = (const float4*)(embed + (size_t)ids[s] * HDIM);
  float4 v0 = src[t], v1 = src[t + 256];
  uint2* xr = (uint2*)(x + (size_t)s * HDIM);
  xr[t]       = make_uint2(pk2(v0.x, v0.y), pk2(v0.z, v0.w));
  xr[t + 256] = make_uint2(pk2(v1.x, v1.y), pk2(v1.z, v1.w));
  if (t < 64) {
    float inv = expf(-(float)t * (9.210340371976184f / 64.0f));  // theta^(-t/64)
    float f = (float)s * inv;
    ct[s * 64 + t] = cosf(f);
    st[s * 64 + t] = sinf(f);
  }
  rms_finish(v0, v1, ln1w, h, s, t, 0);   // layer-0 ln1 output (bf16)
}

// x(bf16) += sum of NPARTS K-split partials (bf16, fixed order), then norm.
template<int OUTF32, int NPARTS>
__global__ __launch_bounds__(256) void rmsnorm_combine_kernel(
    unsigned short* __restrict__ x, const unsigned short* __restrict__ parts,
    const float* __restrict__ w, void* __restrict__ outp) {
  int s = blockIdx.x, t = threadIdx.x;
  const size_t PS = (size_t)2048 * 2048;
  uint2* xr = (uint2*)(x + (size_t)s * HDIM);
  uint2 xa = xr[t], xb = xr[t + 256];
  float4 v0 = make_float4(b2f((unsigned short)xa.x), b2f((unsigned short)(xa.x >> 16)),
                          b2f((unsigned short)xa.y), b2f((unsigned short)(xa.y >> 16)));
  float4 v1 = make_float4(b2f((unsigned short)xb.x), b2f((unsigned short)(xb.x >> 16)),
                          b2f((unsigned short)xb.y), b2f((unsigned short)(xb.y >> 16)));
  #pragma unroll
  for (int p = 0; p < NPARTS; ++p) {
    const unsigned short* pr = parts + p * PS + (size_t)s * HDIM;
    uint2 a = *(const uint2*)(pr + t * 4);
    uint2 b = *(const uint2*)(pr + (t + 256) * 4);
    v0.x += b2f((unsigned short)a.x); v0.y += b2f((unsigned short)(a.x >> 16));
    v0.z += b2f((unsigned short)a.y); v0.w += b2f((unsigned short)(a.y >> 16));
    v1.x += b2f((unsigned short)b.x); v1.y += b2f((unsigned short)(b.x >> 16));
    v1.z += b2f((unsigned short)b.y); v1.w += b2f((unsigned short)(b.y >> 16));
  }
  xr[t]       = make_uint2(pk2(v0.x, v0.y), pk2(v0.z, v0.w));
  xr[t + 256] = make_uint2(pk2(v1.x, v1.y), pk2(v1.z, v1.w));
  rms_finish(v0, v1, w, outp, s, t, OUTF32);
}

// ---------------------------------------------------------------- weight transpose+cvt
// [128 k][64 n] input tiles -> out[n][k] bf16, packed u32 stores.
// Wg/Wu packed interleaved by 128-feature blocks (for fused silu epilogue).
__global__ __launch_bounds__(256) void convert_weights_kernel(
    const float* __restrict__ Wq, const float* __restrict__ Wk,
    const float* __restrict__ Wv, const float* __restrict__ Wo,
    const float* __restrict__ Wg, const float* __restrict__ Wu,
    const float* __restrict__ Wd,
    unsigned short* wqkvT, unsigned short* woT,
    unsigned short* wguT, unsigned short* wdT) {
  __shared__ float tl[128 * 65];
  int b = blockIdx.x;
  const float* in; unsigned short* out; int istr, ostr, tilesN, t; int guAdd = -1;
  if (b < 512)       { in = Wq; out = wqkvT;                       istr = 2048; ostr = 2048; tilesN = 32; t = b; }
  else if (b < 768)  { in = Wk; out = wqkvT + (size_t)2048 * 2048; istr = 1024; ostr = 2048; tilesN = 16; t = b - 512; }
  else if (b < 1024) { in = Wv; out = wqkvT + (size_t)3072 * 2048; istr = 1024; ostr = 2048; tilesN = 16; t = b - 768; }
  else if (b < 1536) { in = Wo; out = woT;                         istr = 2048; ostr = 2048; tilesN = 32; t = b - 1024; }
  else if (b < 2944) { in = Wg; out = wguT;                        istr = 5632; ostr = 2048; tilesN = 88; t = b - 1536; guAdd = 0; }
  else if (b < 4352) { in = Wu; out = wguT;                        istr = 5632; ostr = 2048; tilesN = 88; t = b - 2944; guAdd = 128; }
  else               { in = Wd; out = wdT;                         istr = 2048; ostr = 5632; tilesN = 32; t = b - 4352; }
  int k0 = (t / tilesN) * 128, n0 = (t % tilesN) * 64;
  int tx = threadIdx.x & 63, ty = threadIdx.x >> 6;
  #pragma unroll
  for (int i = 0; i < 32; ++i)
    tl[(ty + 4 * i) * 65 + tx] = in[(size_t)(k0 + ty + 4 * i) * istr + (n0 + tx)];
  __syncthreads();
  int ob = (guAdd >= 0) ? (((n0 >> 7) << 8) + (n0 & 64) + guAdd) : n0;
  unsigned int* ou = (unsigned int*)out;
  const int kstr2 = ostr >> 1;
  #pragma unroll
  for (int i = 0; i < 16; ++i) {
    int nrow = ty + 4 * i;
    float lo = tl[(2 * tx) * 65 + nrow], hi = tl[(2 * tx + 1) * 65 + nrow];
    ou[(size_t)(ob + nrow) * kstr2 + (k0 >> 1) + tx] =
        (unsigned int)f2b(lo) | ((unsigned int)f2b(hi) << 16);
  }
}

// ---------------------------------------------------------------- shared GEMM helpers
DEVI bf16x8 ldsAB(const unsigned short* buf, int r, int cbyte) {
  return *(const bf16x8*)((const unsigned char*)buf + r * 128 + (cbyte ^ ((r & 7) << 4)));
}
DEVI void stage_unit(const unsigned short* __restrict__ G, int Kstr,
                     unsigned short* lbuf, int loff0, int grow0,
                     int loff1, int grow1, int w, int l) {
  const int rsub = l >> 3;
  const int ce = ((l & 7) ^ rsub) << 3;           // pre-swizzled source col
  const unsigned short* s0 = G + (size_t)(grow0 + w * 8 + rsub) * Kstr + ce;
  GLD(s0, (unsigned char*)lbuf + loff0 + w * 1024 + l * 16);
  const unsigned short* s1 = G + (size_t)(grow1 + w * 8 + rsub) * Kstr + ce;
  GLD(s1, (unsigned char*)lbuf + loff1 + w * 1024 + l * 16);
}

// ---------------------------------------------------------------- 128x256 deep-pipelined GEMM (R10-proven best)
// 8 waves (2Mx4N), BK=64. ONE barrier per K-tile, race-free by construction:
// B is TRIPLE-buffered (slot = k mod 3, rotating pointers), A double (parity).
template<int Q>
DEVI void phase128(const unsigned short* Ab, f32x4 (&acc)[4][4],
                   bf16x8 (&breg)[2][4], int wr, int lg, int li) {
  const int r0 = wr * 64 + Q * 16 + li;
  bf16x8 a0 = ldsAB(Ab, r0, lg * 16);
  bf16x8 a1 = ldsAB(Ab, r0, 64 + lg * 16);
  __builtin_amdgcn_s_setprio(1);
  #pragma unroll
  for (int n = 0; n < 4; ++n) acc[Q][n] = mfma16(a0, breg[0][n], acc[Q][n]);
  #pragma unroll
  for (int n = 0; n < 4; ++n) acc[Q][n] = mfma16(a1, breg[1][n], acc[Q][n]);
  __builtin_amdgcn_s_setprio(0);
}

// EPI: 0 = bf16 partial store; 3 = fused silu(g)*u; 4 = qkv epilogue
template<int EPI>
__global__ __launch_bounds__(512, 1) void gemm128_kernel(
    const unsigned short* __restrict__ A, const unsigned short* __restrict__ Bt,
    void* __restrict__ Cout, int Kstr, int nt, int parts, int nbm, int ldc,
    long long partStride,
    const float* __restrict__ ct, const float* __restrict__ st,
    unsigned short* __restrict__ ko, unsigned short* __restrict__ vt) {
  __shared__ __align__(16) unsigned char smem[131072];
  unsigned short* As0 = (unsigned short*)smem;             // [2][128*64] elems (16KB each)
  unsigned short* Bs0 = (unsigned short*)(smem + 32768);   // [3][256*64] elems (32KB each)
  const int tid = threadIdx.x, l = tid & 63, w = tid >> 6;
  const int lg = l >> 4, li = l & 15;
  const int wr = w >> 2, wc = w & 3;
  const int nb = gridDim.x, qx = nb >> 3;
  const int wg = ((int)blockIdx.x & 7) * qx + ((int)blockIdx.x >> 3);  // XCD swizzle (nb%8==0)
  const int nbT = nb / parts;
  const int tile = wg % nbT, part = wg / nbT;
  const int m0 = (tile % nbm) * 128, n0 = (tile / nbm) * 256;  // column-major: B-panel L2 reuse
  const int kOff = part * (nt << 6);
  const unsigned short* At  = A  + (size_t)m0 * Kstr + kOff;
  const unsigned short* Bto = Bt + (size_t)n0 * Kstr + kOff;
  f32x4 acc[4][4] = {};
  bf16x8 breg[2][4];
  unsigned short* B0p = Bs0;                // holds B(t)   (read slot)
  unsigned short* B1p = Bs0 + 16384;        // holds B(t+1)
  unsigned short* B2p = Bs0 + 32768;        // stage target B(t+2)

  // prologue: B(0)x4, A(0)x2, B(1)x4 -> vmcnt(4) retires B(0)+A(0); barrier publishes
  stage_unit(Bto, Kstr, B0p, 0, 0, 8192, 64, w, l);
  stage_unit(Bto, Kstr, B0p, 16384, 128, 24576, 192, w, l);
  stage_unit(At,  Kstr, As0, 0, 0, 8192, 64, w, l);
  { int k1 = (nt > 1) ? 64 : 0;
    stage_unit(Bto + k1, Kstr, B1p, 0, 0, 8192, 64, w, l);
    stage_unit(Bto + k1, Kstr, B1p, 16384, 128, 24576, 192, w, l); }
  asm volatile("s_waitcnt vmcnt(4)\n\ts_barrier" ::: "memory");

  for (int t = 0; t < nt; ++t) {
    unsigned short* Ab  = As0 + (t & 1) * 8192;
    unsigned short* Abn = As0 + ((t & 1) ^ 1) * 8192;
    const int kt1 = ((t + 1 < nt) ? t + 1 : nt - 1) << 6;   // clamped tail keeps queue uniform
    const int kt2 = ((t + 2 < nt) ? t + 2 : nt - 1) << 6;
    // ph0: stage A(t+1) -> other A slot; breg(t) from B0p (published last barrier)
    stage_unit(At + kt1, Kstr, Abn, 0, 0, 8192, 64, w, l);
    #pragma unroll
    for (int ks = 0; ks < 2; ++ks)
      #pragma unroll
      for (int n = 0; n < 4; ++n)
        breg[ks][n] = ldsAB(B0p, wc * 64 + n * 16 + li, ks * 64 + lg * 16);
    phase128<0>(Ab, acc, breg, wr, lg, li);
    // ph1: stage B0(t+2) -> B2p (dead slot; no read conflict this tile)
    stage_unit(Bto + kt2, Kstr, B2p, 0, 0, 8192, 64, w, l);
    phase128<1>(Ab, acc, breg, wr, lg, li);
    // ph2: stage B1(t+2) -> B2p
    stage_unit(Bto + kt2, Kstr, B2p, 16384, 128, 24576, 192, w, l);
    phase128<2>(Ab, acc, breg, wr, lg, li);
    // ph3
    phase128<3>(Ab, acc, breg, wr, lg, li);
    // single per-tile sync: retires B(t+1)+A(t+1) in every wave, then publishes
    asm volatile("s_waitcnt vmcnt(4) lgkmcnt(0)\n\ts_barrier" ::: "memory");
    unsigned short* tmp = B0p; B0p = B1p; B1p = B2p; B2p = tmp;
  }
  asm volatile("s_waitcnt vmcnt(0)" ::: "memory");

  if (EPI == 0) {
    unsigned short* C = (unsigned short*)Cout + (size_t)part * (size_t)partStride;
    #pragma unroll
    for (int m = 0; m < 4; ++m)
      #pragma unroll
      for (int n = 0; n < 4; ++n) {
        int col = n0 + wc * 64 + n * 16 + li;
        #pragma unroll
        for (int r = 0; r < 4; ++r) {
          int row = m0 + wr * 64 + m * 16 + lg * 4 + r;
          C[(size_t)row * ldc + col] = f2b(acc[m][n][r]);
        }
      }
  } else if (EPI == 3) {
    // fused silu: tile cols [0,128) = G features, [128,256) = matching U.
    float* ub = (float*)smem;   // [128][128] f32 = 64KB (LDS reuse after drain)
    asm volatile("s_barrier" ::: "memory");
    if (wc >= 2) {
      #pragma unroll
      for (int m = 0; m < 4; ++m)
        #pragma unroll
        for (int n = 0; n < 4; ++n) {
          int colL = (wc - 2) * 64 + n * 16 + li;
          #pragma unroll
          for (int r = 0; r < 4; ++r) {
            int rowl = wr * 64 + m * 16 + lg * 4 + r;
            ub[rowl * 128 + colL] = acc[m][n][r];
          }
        }
    }
    asm volatile("s_waitcnt lgkmcnt(0)\n\ts_barrier" ::: "memory");
    if (wc < 2) {
      unsigned short* act = (unsigned short*)Cout;
      const int col0 = n0 >> 1;
      #pragma unroll
      for (int m = 0; m < 4; ++m)
        #pragma unroll
        for (int n = 0; n < 4; ++n) {
          int colL = wc * 64 + n * 16 + li;
          #pragma unroll
          for (int r = 0; r < 4; ++r) {
            int rowl = wr * 64 + m * 16 + lg * 4 + r;
            float g = acc[m][n][r];
            float u = ub[rowl * 128 + colL];
            act[(size_t)(m0 + rowl) * ldc + col0 + colL] =
                f2b(g / (1.0f + __expf(-g)) * u);
          }
        }
    }
  } else {
    // EPI == 4: qkv epilogue. Dump acc to LDS f32 [128][256], then per region:
    // Q/K: RoPE with partner at colL^64 -> bf16. V: transposed write to vt[d][s].
    float* dump = (float*)smem;
    asm volatile("s_barrier" ::: "memory");       // all waves drained vmcnt(0)
    #pragma unroll
    for (int m = 0; m < 4; ++m)
      #pragma unroll
      for (int n = 0; n < 4; ++n) {
        int colL = wc * 64 + n * 16 + li;
        #pragma unroll
        for (int r = 0; r < 4; ++r) {
          int rowl = wr * 64 + m * 16 + lg * 4 + r;
          dump[rowl * 256 + colL] = acc[m][n][r];
        }
      }
    asm volatile("s_waitcnt lgkmcnt(0)\n\ts_barrier" ::: "memory");
    if (n0 < 3072) {
      unsigned short* qk = (n0 < 2048) ? (unsigned short*)Cout : ko;
      const int cbase = (n0 < 2048) ? n0 : (n0 - 2048);
      const int ostr  = (n0 < 2048) ? 2048 : 1024;
      #pragma unroll
      for (int m = 0; m < 4; ++m)
        #pragma unroll
        for (int n = 0; n < 4; ++n) {
          int colL = wc * 64 + n * 16 + li;
          int hi = colL & 64;
          #pragma unroll
          for (int r = 0; r < 4; ++r) {
            int rowl = wr * 64 + m * 16 + lg * 4 + r;
            int s = m0 + rowl;
            float own = dump[rowl * 256 + colL];
            float par = dump[rowl * 256 + (colL ^ 64)];
            float c  = ct[s * 64 + (colL & 63)];
            float sn = st[s * 64 + (colL & 63)];
            float v = hi ? (own * c + par * sn) : (own * c - par * sn);
            qk[(size_t)s * ostr + cbase + colL] = f2b(v);
          }
        }
    } else {
      // 512 threads -> 256 vcols x 2 s-halves; 64 bf16 (128B) contiguous per thread
      int vcol = tid >> 1, sh = (tid & 1) * 64;
      unsigned short* dstp = vt + (size_t)(n0 - 3072 + vcol) * 2048 + m0 + sh;
      #pragma unroll
      for (int c8 = 0; c8 < 8; ++c8) {
        unsigned short pk[8];
        #pragma unroll
        for (int i = 0; i < 8; ++i)
          pk[i] = f2b(dump[(sh + c8 * 8 + i) * 256 + vcol]);
        *(uint4*)(dstp + c8 * 8) = *(const uint4*)pk;
      }
    }
  }
}

// ---------------------------------------------------------------- sliding-window flash attention v2 + T13 defer-max
// block = (q-tile 64, kv-head); 8 waves: w0-3 -> head 2kv, w4-7 -> head 2kv+1.
// K/V staged once per pair, double-buffered (stage next before compute).
DEVI void stageKV(const unsigned short* __restrict__ kg,
                  const unsigned short* __restrict__ vtg, int kv, int j0,
                  unsigned short* Kbuf, unsigned short* Vbuf, int w, int l) {
  #pragma unroll
  for (int p = 0; p < 2; ++p) {
    int off = p * 8192 + w * 1024 + l * 16;
    int row = off >> 8;
    int colb = (off & 255) ^ ((row & 7) << 4);
    GLD(kg + (size_t)(j0 + row) * (NKV * HD) + kv * HD + (colb >> 1),
        (unsigned char*)Kbuf + off);
  }
  #pragma unroll
  for (int p = 0; p < 2; ++p) {
    int off = p * 8192 + w * 1024 + l * 16;
    int d = off >> 7;
    int colb = (off & 127) ^ ((d & 7) << 4);
    GLD(vtg + (size_t)(kv * HD + d) * S_LEN + j0 + (colb >> 1),
        (unsigned char*)Vbuf + off);
  }
}

__global__ __launch_bounds__(512) void attn_kernel(
    const unsigned short* __restrict__ qg, const unsigned short* __restrict__ kg,
    const unsigned short* __restrict__ vtg, unsigned short* __restrict__ og) {
  __shared__ __align__(16) unsigned short Kl[2][64 * 128];
  __shared__ __align__(16) unsigned short Vtl[2][128 * 64];
  __shared__ __align__(16) unsigned short Plds[8][16 * 72];
  const int tid = threadIdx.x, l = tid & 63, w = tid >> 6;
  const int lg = l >> 4, li = l & 15;
  const int i0 = blockIdx.x * 64, kv = blockIdx.y;
  const int hq = kv * 2 + (w >> 2);
  const int qr0 = i0 + (w & 3) * 16;
  const float scale = 0.08838834764831845f;

  bf16x8 qf[4];
  {
    const unsigned short* qrow = qg + (size_t)(qr0 + li) * (NH * HD) + hq * HD;
    #pragma unroll
    for (int sl = 0; sl < 4; ++sl)
      qf[sl] = *(const bf16x8*)(qrow + sl * 32 + lg * 8);
  }
  f32x4 oacc[8] = {};
  float mrow[4] = {-1e30f, -1e30f, -1e30f, -1e30f};
  float srow[4] = {0.f, 0.f, 0.f, 0.f};

  int jstart = i0 - WIN; if (jstart < 0) jstart = 0;
  stageKV(kg, vtg, kv, jstart, Kl[0], Vtl[0], w, l);

  int it = 0;
  for (int j0 = jstart; j0 <= i0; j0 += 64, ++it) {
    const int cur = it & 1;
    asm volatile("s_waitcnt vmcnt(0) lgkmcnt(0)\n\ts_barrier" ::: "memory");
    if (j0 + 64 <= i0)
      stageKV(kg, vtg, kv, j0 + 64, Kl[cur ^ 1], Vtl[cur ^ 1], w, l);
    const unsigned short* Klds  = Kl[cur];
    const unsigned short* Vtlds = Vtl[cur];

    f32x4 sacc[4] = {};
    #pragma unroll
    for (int nt = 0; nt < 4; ++nt) {
      int kr = nt * 16 + li;
      #pragma unroll
      for (int sl = 0; sl < 4; ++sl) {
        int cb = (sl * 64 + lg * 16) ^ ((kr & 7) << 4);
        bf16x8 kf = *(const bf16x8*)&Klds[(kr * 256 + cb) >> 1];
        sacc[nt] = mfma16(qf[sl], kf, sacc[nt]);
      }
    }

    float pv[4][4];
    float sval[4][4], pmax[4];
    #pragma unroll
    for (int r = 0; r < 4; ++r) {
      int qi = qr0 + lg * 4 + r;
      float tm = -1e30f;
      #pragma unroll
      for (int nt = 0; nt < 4; ++nt) {
        int j = j0 + nt * 16 + li;
        bool ok = (j <= qi) && (j + WIN >= qi);
        float sv = ok ? sacc[nt][r] * scale : -1e30f;
        sval[r][nt] = sv;
        tm = fmaxf(tm, sv);
      }
      pmax[r] = tm;
    }
    // T13 defer-max: skip max-reduce + rescale when growth bounded (P <= e^8)
    bool cond = (pmax[0] - mrow[0] <= 8.f) && (pmax[1] - mrow[1] <= 8.f) &&
                (pmax[2] - mrow[2] <= 8.f) && (pmax[3] - mrow[3] <= 8.f);
    if (__all(cond)) {
      #pragma unroll
      for (int r = 0; r < 4; ++r) {
        float rs = 0.f;
        #pragma unroll
        for (int nt = 0; nt < 4; ++nt) {
          float p = (sval[r][nt] > -9e29f) ? __expf(sval[r][nt] - mrow[r]) : 0.f;
          pv[nt][r] = p;
          rs += p;
        }
        #pragma unroll
        for (int off2 = 1; off2 < 16; off2 <<= 1)
          rs += __shfl_xor(rs, off2, 64);
        srow[r] += rs;
      }
    } else {
      #pragma unroll
      for (int r = 0; r < 4; ++r) {
        float tm = pmax[r];
        #pragma unroll
        for (int off2 = 1; off2 < 16; off2 <<= 1)
          tm = fmaxf(tm, __shfl_xor(tm, off2, 64));
        float mnew = fmaxf(mrow[r], tm);
        float resc = __expf(mrow[r] - mnew);
        mrow[r] = mnew;
        float rs = 0.f;
        #pragma unroll
        for (int nt = 0; nt < 4; ++nt) {
          float p = (sval[r][nt] > -9e29f) ? __expf(sval[r][nt] - mnew) : 0.f;
          pv[nt][r] = p;
          rs += p;
        }
        #pragma unroll
        for (int off2 = 1; off2 < 16; off2 <<= 1)
          rs += __shfl_xor(rs, off2, 64);
        srow[r] = srow[r] * resc + rs;
        #pragma unroll
        for (int dt = 0; dt < 8; ++dt) oacc[dt][r] *= resc;
      }
    }

    #pragma unroll
    for (int r = 0; r < 4; ++r)
      #pragma unroll
      for (int nt = 0; nt < 4; ++nt)
        Plds[w][(lg * 4 + r) * 72 + nt * 16 + li] = f2b(pv[nt][r]);
    bf16x8 ap[2];
    #pragma unroll
    for (int ks = 0; ks < 2; ++ks)
      ap[ks] = *(const bf16x8*)&Plds[w][li * 72 + ks * 32 + lg * 8];
    #pragma unroll
    for (int dt = 0; dt < 8; ++dt) {
      int d = dt * 16 + li;
      #pragma unroll
      for (int ks = 0; ks < 2; ++ks) {
        int cb = (ks * 64 + lg * 16) ^ ((d & 7) << 4);
        bf16x8 vf = *(const bf16x8*)&Vtlds[(d * 128 + cb) >> 1];
        oacc[dt] = mfma16(ap[ks], vf, oacc[dt]);
      }
    }
  }

  #pragma unroll
  for (int r = 0; r < 4; ++r) {
    float inv = 1.0f / srow[r];
    int qi = qr0 + lg * 4 + r;
    unsigned short* orow = og + (size_t)qi * (NH * HD) + hq * HD;
    #pragma unroll
    for (int dt = 0; dt < 8; ++dt)
      orow[dt * 16 + li] = f2b(oacc[dt][r] * inv);
  }
}

// ---------------------------------------------------------------- launch
extern "C" void kernel_launch(void* const* d_in, const int* in_sizes, int n_in,
                              void* d_out, int out_size, void* d_ws, size_t ws_size,
                              hipStream_t stream) {
  const int*   ids   = (const int*)d_in[0];
  const float* embed = (const float*)d_in[1];
  const float* Wq    = (const float*)d_in[2];
  const float* Wk    = (const float*)d_in[3];
  const float* Wv    = (const float*)d_in[4];
  const float* Wo    = (const float*)d_in[5];
  const float* Wg    = (const float*)d_in[6];
  const float* Wu    = (const float*)d_in[7];
  const float* Wd    = (const float*)d_in[8];
  const float* ln1   = (const float*)d_in[9];
  const float* ln2   = (const float*)d_in[10];
  const float* normw = (const float*)d_in[11];

  uint8_t* ws = (uint8_t*)d_ws;
  unsigned short* wqkvT = (unsigned short*)(ws + 0);            // [4096][2048] bf16
  unsigned short* woT   = (unsigned short*)(ws + 16777216ull);  // [2048][2048]
  unsigned short* wguT  = (unsigned short*)(ws + 25165824ull);  // [11264][2048] packed G/U
  unsigned short* wdT   = (unsigned short*)(ws + 71303168ull);  // [2048][5632]
  unsigned short* x     = (unsigned short*)(ws + 94371840ull);  // residual bf16
  unsigned short* h     = (unsigned short*)(ws + 111149056ull); // rmsnorm out bf16
  unsigned short* q     = (unsigned short*)(ws + 119537664ull); // [S][16][128]
  unsigned short* k     = (unsigned short*)(ws + 127926272ull); // [S][8][128]
  unsigned short* vt    = (unsigned short*)(ws + 132120576ull); // [8][128][S]
  unsigned short* o     = (unsigned short*)(ws + 136314880ull); // [S][2048]
  unsigned short* act   = (unsigned short*)(ws + 119537664ull); // overlays q/k/vt/o (dead)
  unsigned short* pbuf  = (unsigned short*)(ws + 144703488ull); // bf16 K-split partials
  float*          cost  = (float*)(ws + 213909504ull);
  float*          sint  = (float*)(ws + 214433792ull);
  const long long PSel = 4194304LL;   // partial stride (2048*2048 elems bf16)

  gather_kernel<<<2048, 256, 0, stream>>>(ids, embed, x, cost, sint, ln1, h);

  for (int l = 0; l < 2; ++l) {
    convert_weights_kernel<<<5760, 256, 0, stream>>>(
        Wq + (size_t)l * 2048 * 2048, Wk + (size_t)l * 2048 * 1024,
        Wv + (size_t)l * 2048 * 1024, Wo + (size_t)l * 2048 * 2048,
        Wg + (size_t)l * 2048 * 5632, Wu + (size_t)l * 2048 * 5632,
        Wd + (size_t)l * 5632 * 2048,
        wqkvT, woT, wguT, wdT);
    if (l == 1)
      rmsnorm_combine_kernel<0, 2><<<2048, 256, 0, stream>>>(x, pbuf, ln1 + 2048, h);
    // QKV: 256 blocks, fused RoPE + V-transpose epilogue (writes q, k, vt)
    gemm128_kernel<4><<<256, 512, 0, stream>>>(h, wqkvT, q, 2048, 32, 1, 16, 2048, 0,
                                               cost, sint, k, vt);
    attn_kernel<<<dim3(32, 8), 512, 0, stream>>>(q, k, vt, o);
    // O-proj: 128 tiles x splitK2 = 256 blocks, bf16 partials
    gemm128_kernel<0><<<256, 512, 0, stream>>>(o, woT, pbuf, 2048, 16, 2, 16, 2048, PSel,
                                               nullptr, nullptr, nullptr, nullptr);
    rmsnorm_combine_kernel<0, 2><<<2048, 256, 0, stream>>>(x, pbuf, ln2 + l * 2048, h);
    // gate/up fused silu: 16x44 = 704 blocks (4-phase 128x256, 92% packing)
    gemm128_kernel<3><<<704, 512, 0, stream>>>(h, wguT, act, 2048, 32, 1, 16, 5632, 0,
                                               nullptr, nullptr, nullptr, nullptr);
    // down: 128 tiles x splitK2 = 256 blocks, bf16 partials
    gemm128_kernel<0><<<256, 512, 0, stream>>>(act, wdT, pbuf, 5632, 44, 2, 16, 2048, PSel,
                                               nullptr, nullptr, nullptr, nullptr);
  }
  rmsnorm_combine_kernel<1, 2><<<2048, 256, 0, stream>>>(x, pbuf, normw, d_out);
  (void)in_sizes; (void)n_in; (void)out_size; (void)ws_size;
}